// Round 2
// baseline (1811.147 us; speedup 1.0000x reference)
//
#include <hip/hip_runtime.h>
#include <hip/hip_fp16.h>

#define NB   256
#define NS   1024
#define NI   64
#define NH   128
#define NCLS 10

typedef _Float16 h1;
typedef h1 h2 __attribute__((ext_vector_type(2)));

struct alignas(16) H8 { h2 v[4]; };

__device__ __forceinline__ h2 mk2(float a, float b) {
  h2 r; r[0] = (h1)a; r[1] = (h1)b; return r;
}

__device__ __forceinline__ float fdot2(h2 a, h2 b, float c) {
#if __has_builtin(__builtin_amdgcn_fdot2)
  return __builtin_amdgcn_fdot2(a, b, c, false);
#else
  return c + (float)a[0] * (float)b[0] + (float)a[1] * (float)b[1];
#endif
}

__device__ __forceinline__ float fast_rcp(float x) {
#if __has_builtin(__builtin_amdgcn_rcpf)
  return __builtin_amdgcn_rcpf(x);
#else
  return 1.0f / x;
#endif
}

// tanh(x) = 2*sigmoid(2x) - 1; saturates correctly via exp/rcp.
__device__ __forceinline__ float tanh_f(float x) {
  return 2.f * fast_rcp(1.f + __expf(-2.f * x)) - 1.f;
}

__global__ __launch_bounds__(512, 1) void grud_fused(
    const float* __restrict__ values,
    const int*   __restrict__ masks,
    const float* __restrict__ deltas,
    const float* __restrict__ W_dh, const float* __restrict__ b_dh,
    const float* __restrict__ W_dx, const float* __restrict__ b_dx,
    const float* __restrict__ W_ih, const float* __restrict__ W_hh,
    const float* __restrict__ b_ih, const float* __restrict__ b_hh,
    const float* __restrict__ W_out, const float* __restrict__ b_out,
    float* __restrict__ out)
{
  const int b   = blockIdx.x;     // batch row
  const int tid = threadIdx.x;    // 0..511
  const int l   = tid & 63;       // lane
  const int w   = tid >> 6;       // wave 0..7
  const int gt  = l & 3;          // gate type: 0=i 1=f 2=g 3=o
  const int j   = (w << 4) | (l >> 2);  // hidden unit 0..127
  const int n   = (gt << 7) | j;        // gate row 0..511

  __shared__ alignas(16) h2 inp_lds[2][64];  // [buf][pair]: x_h[0:64] ++ m[0:64] as f16
  __shared__ alignas(16) h2 h_lds[2][64];    // decayed h, f16
  __shared__ float hfin[NH];

  // ---- per-thread weights in registers (f16 packed) ----
  h2 wih[64], whh[64];
  {
    const float4* a4 = reinterpret_cast<const float4*>(W_ih + (size_t)n * 128);
    const float4* c4 = reinterpret_cast<const float4*>(W_hh + (size_t)n * 128);
#pragma unroll
    for (int k = 0; k < 32; ++k) {
      float4 a = a4[k];
      wih[2*k]   = mk2(a.x, a.y);
      wih[2*k+1] = mk2(a.z, a.w);
      float4 c = c4[k];
      whh[2*k]   = mk2(c.x, c.y);
      whh[2*k+1] = mk2(c.z, c.w);
    }
  }
  // gamma_h weights: quad-split, lane gt covers k in [16*gt, 16*gt+16)
  float wdhf[16];
  {
    const float4* a4 = reinterpret_cast<const float4*>(W_dh + j * 64 + gt * 16);
#pragma unroll
    for (int k = 0; k < 4; ++k) {
      float4 a = a4[k];
      wdhf[4*k] = a.x; wdhf[4*k+1] = a.y; wdhf[4*k+2] = a.z; wdhf[4*k+3] = a.w;
    }
  }
  const float bias_n = b_ih[n] + b_hh[n];
  const float bdh_j  = b_dh[j];
  float wdx_i = 0.f, bdx_i = 0.f;
  if (tid < NI) { wdx_i = W_dx[tid * 64 + tid]; bdx_i = b_dx[tid]; }

  const size_t base_b = (size_t)b * NS * NI;
  float* out_y   = out;
  float* out_imp = out + NB * NCLS;

  // ---- prologue: h=0, inp[0], impute[0] ----
  if (tid < 64) {
    h_lds[0][tid] = mk2(0.f, 0.f);
    float x0 = values[base_b + tid];
    float m0 = (float)masks[base_b + tid];
    float d0 = deltas[base_b + tid];
    float gx = __expf(-fmaxf(d0 * wdx_i + bdx_i, 0.f));
    float xh = m0 * x0 + (1.f - m0) * (1.f - gx);
    out_imp[base_b + tid] = xh;
    h1* ip = reinterpret_cast<h1*>(&inp_lds[0][0]);
    ip[tid]      = (h1)xh;
    ip[64 + tid] = (h1)m0;
  }

  float c_st = 0.f, h_st = 0.f;
  int cur = 0;

  for (int t = 0; t < NS; ++t) {
    __syncthreads();
    const int    tn = (t + 1 < NS) ? (t + 1) : (NS - 1);
    const size_t nb = base_b + (size_t)tn * NI;

    // phase 1: prefetch next-step inputs (latency hidden under gate dots)
    const float4* dn4 = reinterpret_cast<const float4*>(deltas + nb + gt * 16);
    float4 pd0 = dn4[0], pd1 = dn4[1], pd2 = dn4[2], pd3 = dn4[3];
    float px = 0.f, pm = 0.f, pdv = 0.f;
    if (tid < NI) {
      px  = values[nb + tid];
      pm  = (float)masks[nb + tid];
      pdv = deltas[nb + tid];
    }

    // phase 2: gate_n = bias + inp . W_ih[n] + h . W_hh[n]
    float acc = bias_n;
#pragma unroll
    for (int k = 0; k < 16; ++k) {
      H8 iv = *reinterpret_cast<const H8*>(&inp_lds[cur][4 * k]);
      H8 hv = *reinterpret_cast<const H8*>(&h_lds[cur][4 * k]);
      acc = fdot2(iv.v[0], wih[4*k+0], acc);
      acc = fdot2(iv.v[1], wih[4*k+1], acc);
      acc = fdot2(iv.v[2], wih[4*k+2], acc);
      acc = fdot2(iv.v[3], wih[4*k+3], acc);
      acc = fdot2(hv.v[0], whh[4*k+0], acc);
      acc = fdot2(hv.v[1], whh[4*k+1], acc);
      acc = fdot2(hv.v[2], whh[4*k+2], acc);
      acc = fdot2(hv.v[3], whh[4*k+3], acc);
    }

    // phase 3: activation (g -> tanh, others -> sigmoid)
    float um  = (gt == 2) ? (-2.f * acc) : (-acc);
    float ev  = __expf(um);
    float rv  = fast_rcp(1.f + ev);
    float act = (gt == 2) ? (2.f * rv - 1.f) : rv;

    // phase 4: gather i,f,g,o within the quad (wave-synchronous)
    const int qb = l & ~3;
    float ia = __shfl(act, qb + 0, 64);
    float fa = __shfl(act, qb + 1, 64);
    float ga = __shfl(act, qb + 2, 64);
    float oa = __shfl(act, qb + 3, 64);

    // phase 5: cell update (redundant across the quad; bit-identical)
    c_st = fa * c_st + ia * ga;
    h_st = oa * tanh_f(c_st);

    // phase 6: build inp for t+1 (wave 0 only; whole-wave branch)
    if (tid < NI) {
      float gx = __expf(-fmaxf(pdv * wdx_i + bdx_i, 0.f));
      float xh = pm * px + (1.f - pm) * (1.f - gx);
      if (t + 1 < NS) out_imp[nb + tid] = xh;
      h1* ip = reinterpret_cast<h1*>(&inp_lds[cur ^ 1][0]);
      ip[tid]      = (h1)xh;
      ip[64 + tid] = (h1)pm;
    }

    // phase 7: gamma_h for t+1, write decayed h (f16) to other buffer
    float part = pd0.x*wdhf[0]  + pd0.y*wdhf[1]  + pd0.z*wdhf[2]  + pd0.w*wdhf[3];
    part      += pd1.x*wdhf[4]  + pd1.y*wdhf[5]  + pd1.z*wdhf[6]  + pd1.w*wdhf[7];
    part      += pd2.x*wdhf[8]  + pd2.y*wdhf[9]  + pd2.z*wdhf[10] + pd2.w*wdhf[11];
    part      += pd3.x*wdhf[12] + pd3.y*wdhf[13] + pd3.z*wdhf[14] + pd3.w*wdhf[15];
    part += __shfl_xor(part, 1, 64);
    part += __shfl_xor(part, 2, 64);
    float gh = __expf(-fmaxf(part + bdh_j, 0.f));
    float hd = h_st * gh;
    if (gt == 0) reinterpret_cast<h1*>(&h_lds[cur ^ 1][0])[j] = (h1)hd;

    cur ^= 1;
  }

  // ---- epilogue: y_h = h_final @ W_out^T + b_out ----
  if (gt == 0) hfin[j] = h_st;
  __syncthreads();
  if (tid < NCLS) {
    float acc = b_out[tid];
    const float4* wo4 = reinterpret_cast<const float4*>(W_out + tid * NH);
#pragma unroll
    for (int k = 0; k < 32; ++k) {
      float4 a = wo4[k];
      acc += a.x * hfin[4*k] + a.y * hfin[4*k+1] + a.z * hfin[4*k+2] + a.w * hfin[4*k+3];
    }
    out_y[b * NCLS + tid] = acc;
  }
}

extern "C" void kernel_launch(void* const* d_in, const int* in_sizes, int n_in,
                              void* d_out, int out_size, void* d_ws, size_t ws_size,
                              hipStream_t stream) {
  (void)in_sizes; (void)n_in; (void)d_ws; (void)ws_size; (void)out_size;
  grud_fused<<<dim3(NB), dim3(512), 0, stream>>>(
      (const float*)d_in[0],  (const int*)d_in[1],   (const float*)d_in[2],
      (const float*)d_in[3],  (const float*)d_in[4], (const float*)d_in[5],
      (const float*)d_in[6],  (const float*)d_in[7], (const float*)d_in[8],
      (const float*)d_in[9],  (const float*)d_in[10],(const float*)d_in[11],
      (const float*)d_in[12], (float*)d_out);
}

// Round 4
// 1502.580 us; speedup vs baseline: 1.2054x; 1.2054x over previous
//
#include <hip/hip_runtime.h>
#include <hip/hip_fp16.h>

#define NB   256
#define NS   1024
#define NI   64
#define NH   128
#define NCLS 10

typedef _Float16 h1;
typedef h1 h2 __attribute__((ext_vector_type(2)));
struct alignas(16) H8 { h2 v[4]; };

__device__ __forceinline__ h2 mk2(float a, float b) {
  h2 r; r[0] = (h1)a; r[1] = (h1)b; return r;
}

__device__ __forceinline__ float fdot2(h2 a, h2 b, float c) {
#if __has_builtin(__builtin_amdgcn_fdot2)
  return __builtin_amdgcn_fdot2(a, b, c, false);
#else
  return c + (float)a[0] * (float)b[0] + (float)a[1] * (float)b[1];
#endif
}

__device__ __forceinline__ float fast_rcp(float x) {
#if __has_builtin(__builtin_amdgcn_rcpf)
  return __builtin_amdgcn_rcpf(x);
#else
  return 1.0f / x;
#endif
}

__device__ __forceinline__ float tanh_f(float x) {
  return 2.f * fast_rcp(1.f + __expf(-2.f * x)) - 1.f;
}

__device__ __forceinline__ float sigm(float x) {
  return fast_rcp(1.f + __expf(-x));
}

// VALU-pipe cross-lane add via DPP (keeps the DS pipe free for operand reads).
template<int CTRL>
__device__ __forceinline__ float dpp_add(float x) {
  int y = __builtin_amdgcn_update_dpp(0, __float_as_int(x), CTRL, 0xF, 0xF, true);
  return x + __int_as_float(y);
}
// all-reduce sum over each aligned 8-lane group: xor1, xor2, half-mirror.
// Bit-identical result on all 8 lanes (same association order).
__device__ __forceinline__ float red8(float x) {
  x = dpp_add<0xB1>(x);    // quad_perm {1,0,3,2}
  x = dpp_add<0x4E>(x);    // quad_perm {2,3,0,1}
  x = dpp_add<0x141>(x);   // row_half_mirror
  return x;
}

__global__ __launch_bounds__(1024, 4) void grud_fused(
    const float* __restrict__ values,
    const int*   __restrict__ masks,
    const float* __restrict__ deltas,
    const float* __restrict__ W_dh, const float* __restrict__ b_dh,
    const float* __restrict__ W_dx, const float* __restrict__ b_dx,
    const float* __restrict__ W_ih, const float* __restrict__ W_hh,
    const float* __restrict__ b_ih, const float* __restrict__ b_hh,
    const float* __restrict__ W_out, const float* __restrict__ b_out,
    float* __restrict__ out)
{
  const int b   = blockIdx.x;      // batch row
  const int tid = threadIdx.x;     // 0..1023
  const int l   = tid & 63;
  const int w   = tid >> 6;        // wave 0..15
  const int q   = l & 7;           // K-chunk 0..7 (32 elems each)
  const int g   = l >> 3;          // group in wave 0..7
  const int j   = (w << 3) | g;    // hidden unit 0..127
  const int e0  = q << 5;          // element offset in 256-vec [x_h|m|h]

  // operand vector as f16, double-buffered: [x_h(64) | m(64) | h(128)]
  __shared__ alignas(16) h1 opA[256];
  __shared__ alignas(16) h1 opB[256];
  __shared__ float hfin[NH];

  // ---- per-thread weights: 4 gate rows x 32 f16 (chunk q) ----
  h2 wt0[16], wt1[16], wt2[16], wt3[16];
  {
    const size_t roff = (e0 < 128) ? (size_t)e0 : (size_t)(e0 - 128);
    const float* wbase = (e0 < 128) ? W_ih : W_hh;
#define LOADW(WT, R)                                                          \
    {                                                                         \
      const float4* w4 = reinterpret_cast<const float4*>(                     \
          wbase + ((size_t)((R) * NH + j)) * 128 + roff);                     \
      _Pragma("unroll")                                                       \
      for (int k = 0; k < 8; ++k) {                                           \
        float4 f = w4[k];                                                     \
        WT[2 * k]     = mk2(f.x, f.y);                                        \
        WT[2 * k + 1] = mk2(f.z, f.w);                                        \
      }                                                                       \
    }
    LOADW(wt0, 0) LOADW(wt1, 1) LOADW(wt2, 2) LOADW(wt3, 3)
#undef LOADW
  }
  const float bs0 = b_ih[j]            + b_hh[j];
  const float bs1 = b_ih[NH + j]       + b_hh[NH + j];
  const float bs2 = b_ih[2 * NH + j]   + b_hh[2 * NH + j];
  const float bs3 = b_ih[3 * NH + j]   + b_hh[3 * NH + j];
  // gamma_h weights: unit j, elems [8q, 8q+8) as f16 pairs
  h2 wd0, wd1, wd2, wd3;
  {
    const float4* a4 = reinterpret_cast<const float4*>(W_dh + j * 64 + q * 8);
    float4 f0 = a4[0], f1 = a4[1];
    wd0 = mk2(f0.x, f0.y); wd1 = mk2(f0.z, f0.w);
    wd2 = mk2(f1.x, f1.y); wd3 = mk2(f1.z, f1.w);
  }
  const float bdh = b_dh[j];
  float wdx_i = 0.f, bdx_i = 0.f;
  if (tid < NI) { wdx_i = W_dx[tid * 64 + tid]; bdx_i = b_dx[tid]; }

  const size_t base_b = (size_t)b * NS * NI;
  float* out_y   = out;
  float* out_imp = out + NB * NCLS;

  // ---- prologue: zero h region, build inp[0], impute[0] ----
  if (tid < NH) opA[128 + tid] = (h1)0.f;
  if (tid < NI) {
    float x0 = values[base_b + tid];
    float m0 = (float)masks[base_b + tid];
    float d0 = deltas[base_b + tid];
    float gx = __expf(-fmaxf(d0 * wdx_i + bdx_i, 0.f));
    float xh = m0 * x0 + (1.f - m0) * (1.f - gx);
    out_imp[base_b + tid] = xh;
    opA[tid]      = (h1)xh;
    opA[64 + tid] = (h1)m0;
  }

  h1* cur = opA;
  h1* nxt = opB;
  float c_st = 0.f, h_st = 0.f;

  for (int t = 0; t < NS; ++t) {
    __syncthreads();
    const int    tn = (t + 1 < NS) ? (t + 1) : (NS - 1);
    const size_t nb = base_b + (size_t)tn * NI;

    // prefetch next-step deltas (this thread's 8 elems) + wave-0 impute data
    const float4* dn4 = reinterpret_cast<const float4*>(deltas + nb + q * 8);
    float4 pa = dn4[0], pb = dn4[1];
    float px = 0.f, pm = 0.f, pdv = 0.f;
    if (tid < NI) {
      px  = values[nb + tid];
      pm  = (float)masks[nb + tid];
      pdv = deltas[nb + tid];
    }

    // operand chunk: 32 f16 = 4 x b128
    const H8* s4 = reinterpret_cast<const H8*>(cur + e0);
    H8 o0 = s4[0], o1 = s4[1], o2 = s4[2], o3 = s4[3];

    // 4 gates x 16 dot2 (independent chains)
    float a0 = 0.f, a1 = 0.f, a2 = 0.f, a3 = 0.f;
#pragma unroll
    for (int p = 0; p < 4; ++p) {
      a0 = fdot2(o0.v[p], wt0[p], a0);
      a1 = fdot2(o0.v[p], wt1[p], a1);
      a2 = fdot2(o0.v[p], wt2[p], a2);
      a3 = fdot2(o0.v[p], wt3[p], a3);
    }
#pragma unroll
    for (int p = 0; p < 4; ++p) {
      a0 = fdot2(o1.v[p], wt0[4 + p], a0);
      a1 = fdot2(o1.v[p], wt1[4 + p], a1);
      a2 = fdot2(o1.v[p], wt2[4 + p], a2);
      a3 = fdot2(o1.v[p], wt3[4 + p], a3);
    }
#pragma unroll
    for (int p = 0; p < 4; ++p) {
      a0 = fdot2(o2.v[p], wt0[8 + p], a0);
      a1 = fdot2(o2.v[p], wt1[8 + p], a1);
      a2 = fdot2(o2.v[p], wt2[8 + p], a2);
      a3 = fdot2(o2.v[p], wt3[8 + p], a3);
    }
#pragma unroll
    for (int p = 0; p < 4; ++p) {
      a0 = fdot2(o3.v[p], wt0[12 + p], a0);
      a1 = fdot2(o3.v[p], wt1[12 + p], a1);
      a2 = fdot2(o3.v[p], wt2[12 + p], a2);
      a3 = fdot2(o3.v[p], wt3[12 + p], a3);
    }

    // 8-lane reduce on the VALU pipe; all 8 lanes get all 4 gates
    float gi = red8(a0) + bs0;
    float gf = red8(a1) + bs1;
    float gg = red8(a2) + bs2;
    float go = red8(a3) + bs3;

    float ia = sigm(gi);
    float fa = sigm(gf);
    float ga = tanh_f(gg);
    float oa = sigm(go);

    c_st = fa * c_st + ia * ga;
    h_st = oa * tanh_f(c_st);

    // gamma_h for t+1 (dot over 64 via 8 elems/lane + red8)
    h2 p0 = mk2(pa.x, pa.y), p1 = mk2(pa.z, pa.w);
    h2 p2 = mk2(pb.x, pb.y), p3 = mk2(pb.z, pb.w);
    float part = fdot2(p3, wd3, fdot2(p2, wd2, fdot2(p1, wd1, fdot2(p0, wd0, 0.f))));
    part = red8(part);
    float gh = __expf(-fmaxf(part + bdh, 0.f));

    // build next operand buffer
    if (tid < NI) {
      float gx = __expf(-fmaxf(pdv * wdx_i + bdx_i, 0.f));
      float xh = pm * px + (1.f - pm) * (1.f - gx);
      if (t + 1 < NS) out_imp[nb + tid] = xh;
      nxt[tid]      = (h1)xh;
      nxt[64 + tid] = (h1)pm;
    }
    if (q == 0) nxt[128 + j] = (h1)(h_st * gh);

    h1* tmp = cur; cur = nxt; nxt = tmp;
  }

  // ---- epilogue: y_h = h_final @ W_out^T + b_out ----
  if (q == 0) hfin[j] = h_st;
  __syncthreads();
  if (tid < NCLS) {
    float acc = b_out[tid];
    const float4* wo4 = reinterpret_cast<const float4*>(W_out + tid * NH);
#pragma unroll
    for (int k = 0; k < 32; ++k) {
      float4 a = wo4[k];
      acc += a.x * hfin[4 * k] + a.y * hfin[4 * k + 1] +
             a.z * hfin[4 * k + 2] + a.w * hfin[4 * k + 3];
    }
    out_y[b * NCLS + tid] = acc;
  }
}

extern "C" void kernel_launch(void* const* d_in, const int* in_sizes, int n_in,
                              void* d_out, int out_size, void* d_ws, size_t ws_size,
                              hipStream_t stream) {
  (void)in_sizes; (void)n_in; (void)d_ws; (void)ws_size; (void)out_size;
  grud_fused<<<dim3(NB), dim3(1024), 0, stream>>>(
      (const float*)d_in[0],  (const int*)d_in[1],   (const float*)d_in[2],
      (const float*)d_in[3],  (const float*)d_in[4], (const float*)d_in[5],
      (const float*)d_in[6],  (const float*)d_in[7], (const float*)d_in[8],
      (const float*)d_in[9],  (const float*)d_in[10],(const float*)d_in[11],
      (const float*)d_in[12], (float*)d_out);
}